// Round 2
// baseline (93.783 us; speedup 1.0000x reference)
//
#include <hip/hip_runtime.h>

#define N_SAMPLES 128
#define NUM_OBJECTS 8
#define NUM_POINTS 100000
#define GROUPS 25000           // groups of 4 points (48 B each)
#define TPB 256
#define CHUNKS 49              // ceil(GROUPS / (TPB*2)) ; 2 groups per thread
// group ids: g0 = blockIdx.x*TPB + tid  (< 12544), g1 = g0 + CHUNKS*TPB (guarded)

// Kernel A: zero pm accumulators, compute the two translation losses.
__global__ __launch_bounds__(128) void t_loss_kernel(
    const float* __restrict__ gt_t, const float* __restrict__ pred_t,
    float* __restrict__ out)
{
    int n = threadIdx.x;
    if (n < N_SAMPLES) {
        float dx = fabsf(gt_t[n * 3 + 0] - pred_t[n * 3 + 0]);
        float dy = fabsf(gt_t[n * 3 + 1] - pred_t[n * 3 + 1]);
        float dz = fabsf(gt_t[n * 3 + 2] - pred_t[n * 3 + 2]);
        out[n] = 0.0f;                    // pm accumulator (pm_kernel atomics)
        out[N_SAMPLES + n] = dx + dy;     // t_site_center_loss
        out[2 * N_SAMPLES + n] = dz;      // t_site_depth_loss
    }
}

// 4 packed points from 3 float4s: p0=(a.x,a.y,a.z) p1=(a.w,b.x,b.y)
// p2=(b.z,b.w,c.x) p3=(c.y,c.z,c.w)
__device__ __forceinline__ float pts4_l1(
    float4 a, float4 b, float4 c,
    float d0, float d1, float d2, float d3, float d4,
    float d5, float d6, float d7, float d8)
{
    float s;
    s  = fabsf(d0 * a.x + d1 * a.y + d2 * a.z)
       + fabsf(d3 * a.x + d4 * a.y + d5 * a.z)
       + fabsf(d6 * a.x + d7 * a.y + d8 * a.z);
    s += fabsf(d0 * a.w + d1 * b.x + d2 * b.y)
       + fabsf(d3 * a.w + d4 * b.x + d5 * b.y)
       + fabsf(d6 * a.w + d7 * b.x + d8 * b.y);
    s += fabsf(d0 * b.z + d1 * b.w + d2 * c.x)
       + fabsf(d3 * b.z + d4 * b.w + d5 * c.x)
       + fabsf(d6 * b.z + d7 * b.w + d8 * c.x);
    s += fabsf(d0 * c.y + d1 * c.z + d2 * c.w)
       + fabsf(d3 * c.y + d4 * c.z + d5 * c.w)
       + fabsf(d6 * c.y + d7 * c.z + d8 * c.w);
    return s;
}

// Kernel B: grid = (CHUNKS, NUM_OBJECTS). Each block loads 2048 points of its
// object ONCE into registers, then loops over all samples mapped to that
// object (dR staged in LDS), wave-reduces and atomicAdds per sample.
__global__ __launch_bounds__(TPB) void pm_kernel(
    const int* __restrict__ obj_id,
    const float* __restrict__ gtR, const float* __restrict__ prR,
    const float* __restrict__ pts, const float* __restrict__ diam,
    float* __restrict__ out)
{
    const int o = blockIdx.y;

    __shared__ int   s_cnt;
    __shared__ float s_scale;
    __shared__ int   s_sidx[N_SAMPLES];
    __shared__ float s_dR[N_SAMPLES][9];

    if (threadIdx.x == 0) {
        s_cnt = 0;
        s_scale = 1.0f / ((float)NUM_POINTS * diam[o]);
    }
    __syncthreads();
    if (threadIdx.x < N_SAMPLES) {
        const int n = threadIdx.x;
        if (obj_id[n] == o) {
            int slot = atomicAdd(&s_cnt, 1);
            s_sidx[slot] = n;
            #pragma unroll
            for (int j = 0; j < 9; ++j)
                s_dR[slot][j] = prR[n * 9 + j] - gtR[n * 9 + j];
        }
    }
    __syncthreads();
    const int nsamp = s_cnt;
    if (nsamp == 0) return;
    const float fscale = s_scale;

    // Load 8 points (two groups of 4) into registers, once.
    const float4* __restrict__ p4 =
        (const float4*)(pts + (size_t)o * (size_t)NUM_POINTS * 3);
    const int g0 = blockIdx.x * TPB + threadIdx.x;      // < 12544, always valid
    const int g1 = g0 + CHUNKS * TPB;                   // may exceed GROUPS
    float4 a0 = p4[g0 * 3 + 0], b0 = p4[g0 * 3 + 1], c0 = p4[g0 * 3 + 2];
    float4 a1, b1, c1;
    if (g1 < GROUPS) {
        a1 = p4[g1 * 3 + 0]; b1 = p4[g1 * 3 + 1]; c1 = p4[g1 * 3 + 2];
    } else {
        a1 = make_float4(0.f, 0.f, 0.f, 0.f);
        b1 = a1; c1 = a1;
    }

    const int lane = threadIdx.x & 63;
    for (int s = 0; s < nsamp; ++s) {
        // broadcast LDS reads (same address across lanes -> conflict-free)
        float d0 = s_dR[s][0], d1 = s_dR[s][1], d2 = s_dR[s][2];
        float d3 = s_dR[s][3], d4 = s_dR[s][4], d5 = s_dR[s][5];
        float d6 = s_dR[s][6], d7 = s_dR[s][7], d8 = s_dR[s][8];

        float acc = pts4_l1(a0, b0, c0, d0, d1, d2, d3, d4, d5, d6, d7, d8)
                  + pts4_l1(a1, b1, c1, d0, d1, d2, d3, d4, d5, d6, d7, d8);

        #pragma unroll
        for (int off = 32; off > 0; off >>= 1)
            acc += __shfl_down(acc, off, 64);

        if (lane == 0)
            atomicAdd(&out[s_sidx[s]], acc * fscale);
    }
}

extern "C" void kernel_launch(void* const* d_in, const int* in_sizes, int n_in,
                              void* d_out, int out_size, void* d_ws, size_t ws_size,
                              hipStream_t stream) {
    const int*   obj_id = (const int*)d_in[0];
    const float* gtR    = (const float*)d_in[1];
    const float* prR    = (const float*)d_in[2];
    const float* gt_t   = (const float*)d_in[3];
    const float* pred_t = (const float*)d_in[4];
    const float* pts    = (const float*)d_in[5];
    const float* diam   = (const float*)d_in[6];
    float* out = (float*)d_out;

    t_loss_kernel<<<1, 128, 0, stream>>>(gt_t, pred_t, out);
    pm_kernel<<<dim3(CHUNKS, NUM_OBJECTS), TPB, 0, stream>>>(
        obj_id, gtR, prR, pts, diam, out);
}

// Round 3
// 17.468 us; speedup vs baseline: 5.3689x; 5.3689x over previous
//
#include <hip/hip_runtime.h>

#define N_SAMPLES 128
#define NUM_OBJECTS 8
#define NUM_POINTS 100000
#define GROUPS 25000           // groups of 4 points (48 B / 12 floats each)
#define TPB 256
#define CHUNKS 98              // blocks per object: 98*256 = 25088 >= 25000

// 4 packed points from 12 floats f[0..11]:
// p0=(f0,f1,f2) p1=(f3,f4,f5) p2=(f6,f7,f8) p3=(f9,f10,f11)
__device__ __forceinline__ float pts4_l1(
    const float* __restrict__ f,
    float d0, float d1, float d2, float d3, float d4,
    float d5, float d6, float d7, float d8)
{
    float s;
    s  = fabsf(d0 * f[0] + d1 * f[1]  + d2 * f[2])
       + fabsf(d3 * f[0] + d4 * f[1]  + d5 * f[2])
       + fabsf(d6 * f[0] + d7 * f[1]  + d8 * f[2]);
    s += fabsf(d0 * f[3] + d1 * f[4]  + d2 * f[5])
       + fabsf(d3 * f[3] + d4 * f[4]  + d5 * f[5])
       + fabsf(d6 * f[3] + d7 * f[4]  + d8 * f[5]);
    s += fabsf(d0 * f[6] + d1 * f[7]  + d2 * f[8])
       + fabsf(d3 * f[6] + d4 * f[7]  + d5 * f[8])
       + fabsf(d6 * f[6] + d7 * f[7]  + d8 * f[8]);
    s += fabsf(d0 * f[9] + d1 * f[10] + d2 * f[11])
       + fabsf(d3 * f[9] + d4 * f[10] + d5 * f[11])
       + fabsf(d6 * f[9] + d7 * f[10] + d8 * f[11]);
    return s;
}

// Kernel 1: grid = (CHUNKS, NUM_OBJECTS). Each thread holds 4 points (12
// floats) in registers; loop over the object's samples (dR in LDS, broadcast
// reads); per-sample wave reduce -> LDS partial -> ONE plain store per
// (sample, chunk) into ws. No atomics.
__global__ __launch_bounds__(TPB) void pm_partial_kernel(
    const int* __restrict__ obj_id,
    const float* __restrict__ gtR, const float* __restrict__ prR,
    const float* __restrict__ pts,
    float* __restrict__ ws)
{
    const int o     = blockIdx.y;
    const int chunk = blockIdx.x;

    __shared__ int   s_cnt;
    __shared__ int   s_sidx[N_SAMPLES];
    __shared__ float s_dR[N_SAMPLES][9];
    __shared__ float s_part[TPB / 64][N_SAMPLES];

    if (threadIdx.x == 0) s_cnt = 0;
    __syncthreads();
    if (threadIdx.x < N_SAMPLES) {
        const int n = threadIdx.x;
        if (obj_id[n] == o) {
            int slot = atomicAdd(&s_cnt, 1);   // LDS atomic, one-time
            s_sidx[slot] = n;
            #pragma unroll
            for (int j = 0; j < 9; ++j)
                s_dR[slot][j] = prR[n * 9 + j] - gtR[n * 9 + j];
        }
    }
    __syncthreads();
    const int nsamp = s_cnt;
    if (nsamp == 0) return;   // no sample owns this object -> no ws entries owed

    // Load this thread's 4 points (12 floats) once; zero-scale the tail.
    int g = chunk * TPB + threadIdx.x;
    const float valid = (g < GROUPS) ? 1.0f : 0.0f;
    g = min(g, GROUPS - 1);
    const float4* __restrict__ p4 =
        (const float4*)(pts + (size_t)o * (size_t)NUM_POINTS * 3);
    float4 a = p4[g * 3 + 0];
    float4 b = p4[g * 3 + 1];
    float4 c = p4[g * 3 + 2];
    float f[12] = { a.x * valid, a.y * valid, a.z * valid, a.w * valid,
                    b.x * valid, b.y * valid, b.z * valid, b.w * valid,
                    c.x * valid, c.y * valid, c.z * valid, c.w * valid };

    const int lane = threadIdx.x & 63;
    const int wave = threadIdx.x >> 6;
    for (int s = 0; s < nsamp; ++s) {
        float d0 = s_dR[s][0], d1 = s_dR[s][1], d2 = s_dR[s][2];
        float d3 = s_dR[s][3], d4 = s_dR[s][4], d5 = s_dR[s][5];
        float d6 = s_dR[s][6], d7 = s_dR[s][7], d8 = s_dR[s][8];

        float acc = pts4_l1(f, d0, d1, d2, d3, d4, d5, d6, d7, d8);

        #pragma unroll
        for (int off = 32; off > 0; off >>= 1)
            acc += __shfl_down(acc, off, 64);

        if (lane == 0) s_part[wave][s] = acc;
    }
    __syncthreads();

    if (threadIdx.x < nsamp) {
        const int s = threadIdx.x;
        float v = s_part[0][s] + s_part[1][s] + s_part[2][s] + s_part[3][s];
        ws[(size_t)s_sidx[s] * CHUNKS + chunk] = v;   // plain store, unique slot
    }
}

// Kernel 2: one block (64 threads) per sample. Reduce the 98 chunk partials,
// scale, and also emit the two translation losses. Writes every out element
// exactly once -> no pre-zero kernel needed.
__global__ __launch_bounds__(64) void finish_kernel(
    const int* __restrict__ obj_id, const float* __restrict__ diam,
    const float* __restrict__ gt_t, const float* __restrict__ pred_t,
    const float* __restrict__ ws, float* __restrict__ out)
{
    const int n = blockIdx.x;
    const int t = threadIdx.x;

    float v = ws[(size_t)n * CHUNKS + t];             // t < 64 < CHUNKS
    if (t + 64 < CHUNKS) v += ws[(size_t)n * CHUNKS + t + 64];

    #pragma unroll
    for (int off = 32; off > 0; off >>= 1)
        v += __shfl_down(v, off, 64);

    if (t == 0) {
        out[n] = v / ((float)NUM_POINTS * diam[obj_id[n]]);
    } else if (t == 1) {
        out[N_SAMPLES + n] = fabsf(gt_t[n * 3 + 0] - pred_t[n * 3 + 0])
                           + fabsf(gt_t[n * 3 + 1] - pred_t[n * 3 + 1]);
    } else if (t == 2) {
        out[2 * N_SAMPLES + n] = fabsf(gt_t[n * 3 + 2] - pred_t[n * 3 + 2]);
    }
}

extern "C" void kernel_launch(void* const* d_in, const int* in_sizes, int n_in,
                              void* d_out, int out_size, void* d_ws, size_t ws_size,
                              hipStream_t stream) {
    const int*   obj_id = (const int*)d_in[0];
    const float* gtR    = (const float*)d_in[1];
    const float* prR    = (const float*)d_in[2];
    const float* gt_t   = (const float*)d_in[3];
    const float* pred_t = (const float*)d_in[4];
    const float* pts    = (const float*)d_in[5];
    const float* diam   = (const float*)d_in[6];
    float* out = (float*)d_out;
    float* ws  = (float*)d_ws;   // 128 * 98 * 4 B = 50 KB partials

    pm_partial_kernel<<<dim3(CHUNKS, NUM_OBJECTS), TPB, 0, stream>>>(
        obj_id, gtR, prR, pts, ws);
    finish_kernel<<<N_SAMPLES, 64, 0, stream>>>(
        obj_id, diam, gt_t, pred_t, ws, out);
}

// Round 4
// 17.370 us; speedup vs baseline: 5.3990x; 1.0056x over previous
//
#include <hip/hip_runtime.h>

#define N_SAMPLES 128
#define NUM_OBJECTS 8
#define NUM_POINTS 100000
#define GROUPS 25000           // groups of 4 points (48 B / 12 floats each)
#define TPB 256
#define CHUNKS 98              // blocks per object: 98*256 = 25088 >= 25000
#define MAXS 128               // worst-case samples mapped to one object

// 4 packed points from 12 floats f[0..11]:
// p0=(f0,f1,f2) p1=(f3,f4,f5) p2=(f6,f7,f8) p3=(f9,f10,f11)
__device__ __forceinline__ float pts4_l1(
    const float* __restrict__ f,
    float d0, float d1, float d2, float d3, float d4,
    float d5, float d6, float d7, float d8)
{
    float s;
    s  = fabsf(d0 * f[0] + d1 * f[1]  + d2 * f[2])
       + fabsf(d3 * f[0] + d4 * f[1]  + d5 * f[2])
       + fabsf(d6 * f[0] + d7 * f[1]  + d8 * f[2]);
    s += fabsf(d0 * f[3] + d1 * f[4]  + d2 * f[5])
       + fabsf(d3 * f[3] + d4 * f[4]  + d5 * f[5])
       + fabsf(d6 * f[3] + d7 * f[4]  + d8 * f[5]);
    s += fabsf(d0 * f[6] + d1 * f[7]  + d2 * f[8])
       + fabsf(d3 * f[6] + d4 * f[7]  + d5 * f[8])
       + fabsf(d6 * f[6] + d7 * f[7]  + d8 * f[8]);
    s += fabsf(d0 * f[9] + d1 * f[10] + d2 * f[11])
       + fabsf(d3 * f[9] + d4 * f[10] + d5 * f[11])
       + fabsf(d6 * f[9] + d7 * f[10] + d8 * f[11]);
    return s;
}

// Kernel 1: grid = (CHUNKS, NUM_OBJECTS). Each thread holds 4 points in
// registers; samples processed 4 at a time (4 independent shuffle chains);
// 5-level __shfl_xor reduce (within-32 only), lanes 0 and 32 write half-wave
// partials; one plain ws store per (sample, chunk). No global atomics.
__global__ __launch_bounds__(TPB) void pm_partial_kernel(
    const int* __restrict__ obj_id,
    const float* __restrict__ gtR, const float* __restrict__ prR,
    const float* __restrict__ pts,
    float* __restrict__ ws)
{
    const int o     = blockIdx.y;
    const int chunk = blockIdx.x;

    __shared__ int   s_cnt;
    __shared__ int   s_sidx[MAXS];
    __shared__ float s_dR[MAXS][12];      // rows padded to 12 for b128 reads
    __shared__ float s_part[8][MAXS];     // 8 half-wave partials per sample

    if (threadIdx.x == 0) s_cnt = 0;
    __syncthreads();
    if (threadIdx.x < N_SAMPLES) {
        const int n = threadIdx.x;
        if (obj_id[n] == o) {
            int slot = atomicAdd(&s_cnt, 1);   // LDS atomic, one-time
            s_sidx[slot] = n;
            #pragma unroll
            for (int j = 0; j < 9; ++j)
                s_dR[slot][j] = prR[n * 9 + j] - gtR[n * 9 + j];
        }
    }
    __syncthreads();
    const int nsamp = s_cnt;
    if (nsamp == 0) return;   // nothing owed for this object
    const int nsamp_pad = (nsamp + 3) & ~3;
    // zero the <=3 pad slots so their acc comes out 0
    {
        const int idx = nsamp + (int)threadIdx.x;
        if (idx < nsamp_pad) {
            #pragma unroll
            for (int j = 0; j < 9; ++j) s_dR[idx][j] = 0.0f;
        }
    }
    __syncthreads();

    // Load this thread's 4 points (12 floats) once; zero the tail lanes.
    int g = chunk * TPB + threadIdx.x;
    const float valid = (g < GROUPS) ? 1.0f : 0.0f;
    g = min(g, GROUPS - 1);
    const float4* __restrict__ p4 =
        (const float4*)(pts + (size_t)o * (size_t)NUM_POINTS * 3);
    float4 a = p4[g * 3 + 0];
    float4 b = p4[g * 3 + 1];
    float4 c = p4[g * 3 + 2];
    float f[12] = { a.x * valid, a.y * valid, a.z * valid, a.w * valid,
                    b.x * valid, b.y * valid, b.z * valid, b.w * valid,
                    c.x * valid, c.y * valid, c.z * valid, c.w * valid };

    const int lane = threadIdx.x & 63;
    const int wave = threadIdx.x >> 6;
    const int half = wave * 2 + (lane >> 5);

    for (int s0 = 0; s0 < nsamp_pad; s0 += 4) {
        float acc[4];
        #pragma unroll
        for (int k = 0; k < 4; ++k) {
            float4 q0 = *(const float4*)&s_dR[s0 + k][0];
            float4 q1 = *(const float4*)&s_dR[s0 + k][4];
            float4 q2 = *(const float4*)&s_dR[s0 + k][8];
            acc[k] = pts4_l1(f, q0.x, q0.y, q0.z, q0.w,
                                q1.x, q1.y, q1.z, q1.w, q2.x);
        }
        // 5-level within-32 butterfly, 4 independent chains
        #pragma unroll
        for (int off = 1; off <= 16; off <<= 1) {
            #pragma unroll
            for (int k = 0; k < 4; ++k)
                acc[k] += __shfl_xor(acc[k], off, 64);
        }
        if ((lane & 31) == 0) {
            #pragma unroll
            for (int k = 0; k < 4; ++k)
                s_part[half][s0 + k] = acc[k];
        }
    }
    __syncthreads();

    if (threadIdx.x < nsamp) {
        const int s = threadIdx.x;
        float v = 0.0f;
        #pragma unroll
        for (int w = 0; w < 8; ++w) v += s_part[w][s];
        ws[(size_t)s_sidx[s] * CHUNKS + chunk] = v;   // unique slot, plain store
    }
}

// Kernel 2: one block (64 threads) per sample. Reduce the 98 chunk partials,
// scale, and emit the two translation losses. Writes every out element once.
__global__ __launch_bounds__(64) void finish_kernel(
    const int* __restrict__ obj_id, const float* __restrict__ diam,
    const float* __restrict__ gt_t, const float* __restrict__ pred_t,
    const float* __restrict__ ws, float* __restrict__ out)
{
    const int n = blockIdx.x;
    const int t = threadIdx.x;

    float v = ws[(size_t)n * CHUNKS + t];             // t < 64 < CHUNKS
    if (t + 64 < CHUNKS) v += ws[(size_t)n * CHUNKS + t + 64];

    #pragma unroll
    for (int off = 32; off > 0; off >>= 1)
        v += __shfl_down(v, off, 64);

    if (t == 0) {
        out[n] = v / ((float)NUM_POINTS * diam[obj_id[n]]);
    } else if (t == 1) {
        out[N_SAMPLES + n] = fabsf(gt_t[n * 3 + 0] - pred_t[n * 3 + 0])
                           + fabsf(gt_t[n * 3 + 1] - pred_t[n * 3 + 1]);
    } else if (t == 2) {
        out[2 * N_SAMPLES + n] = fabsf(gt_t[n * 3 + 2] - pred_t[n * 3 + 2]);
    }
}

extern "C" void kernel_launch(void* const* d_in, const int* in_sizes, int n_in,
                              void* d_out, int out_size, void* d_ws, size_t ws_size,
                              hipStream_t stream) {
    const int*   obj_id = (const int*)d_in[0];
    const float* gtR    = (const float*)d_in[1];
    const float* prR    = (const float*)d_in[2];
    const float* gt_t   = (const float*)d_in[3];
    const float* pred_t = (const float*)d_in[4];
    const float* pts    = (const float*)d_in[5];
    const float* diam   = (const float*)d_in[6];
    float* out = (float*)d_out;
    float* ws  = (float*)d_ws;   // 128 * 98 * 4 B = 50 KB partials

    pm_partial_kernel<<<dim3(CHUNKS, NUM_OBJECTS), TPB, 0, stream>>>(
        obj_id, gtR, prR, pts, ws);
    finish_kernel<<<N_SAMPLES, 64, 0, stream>>>(
        obj_id, diam, gt_t, pred_t, ws, out);
}